// Round 3
// baseline (1312.648 us; speedup 1.0000x reference)
//
#include <hip/hip_runtime.h>
#include <stdint.h>

#define NM 10000
#define NG 100000
#define NE 300000
#define DD 256
#define HH 256

typedef unsigned short u16;
typedef float f32x4 __attribute__((ext_vector_type(4)));
typedef short bf16x8 __attribute__((ext_vector_type(8)));

__device__ __forceinline__ u16 f2bf(float f) {
    union { float f; unsigned int i; } v; v.f = f;
    unsigned int x = v.i;
    x += 0x7fffu + ((x >> 16) & 1u);   // RNE
    return (u16)(x >> 16);
}
__device__ __forceinline__ unsigned int pack2(u16 lo, u16 hi) {
    return (unsigned int)lo | ((unsigned int)hi << 16);
}
__device__ __forceinline__ uint4 pack8(float4 v0, float4 v1) {
    uint4 o;
    o.x = pack2(f2bf(v0.x), f2bf(v0.y));
    o.y = pack2(f2bf(v0.z), f2bf(v0.w));
    o.z = pack2(f2bf(v1.x), f2bf(v1.y));
    o.w = pack2(f2bf(v1.z), f2bf(v1.w));
    return o;
}

// ------- weight transpose + downcast: in f32[K][N] -> out bf16[N][K] -------
__global__ void transpose_f32_to_bf16T(const float* __restrict__ in,
                                       u16* __restrict__ out, int K, int N) {
    __shared__ float tile[64][68];        // +4 pad, rows 16B aligned
    const int ntn = N >> 6;
    const int tk = blockIdx.x / ntn;
    const int tn = blockIdx.x % ntn;
    const int k0 = tk << 6, n0 = tn << 6;
    const int tid = threadIdx.x;
    #pragma unroll
    for (int i = 0; i < 4; ++i) {
        int flat = tid + 256 * i;         // 1024 float4 chunks
        int r = flat >> 4;
        int c = (flat & 15) << 2;
        *(float4*)&tile[r][c] = *(const float4*)(in + (size_t)(k0 + r) * N + n0 + c);
    }
    __syncthreads();
    #pragma unroll
    for (int i = 0; i < 2; ++i) {
        int flat = tid + 256 * i;
        int r = flat >> 3;                // output row (n)
        int c = (flat & 7) << 3;          // output col (k), 8 per thread
        uint4 o;
        o.x = pack2(f2bf(tile[c + 0][r]), f2bf(tile[c + 1][r]));
        o.y = pack2(f2bf(tile[c + 2][r]), f2bf(tile[c + 3][r]));
        o.z = pack2(f2bf(tile[c + 4][r]), f2bf(tile[c + 5][r]));
        o.w = pack2(f2bf(tile[c + 6][r]), f2bf(tile[c + 7][r]));
        *(uint4*)(out + (size_t)(n0 + r) * K + k0 + c) = o;
    }
}

// ---------------- edge MLP + scatter-add ----------------
// hT = w1T · edge_inT (swapped-operand MFMA -> D[hidden][edge]), relu+bias ->
// LDS h[edge][hidden] bf16, then w2T · hT, scatter f32 HW atomics into agg
// (= d_out reused as [NG][HH] f32 accumulator).
__global__ __launch_bounds__(256, 2) void edge_mlp(
    const float* __restrict__ mesh_x, const float* __restrict__ grid_x,
    const int* __restrict__ esrc, const int* __restrict__ edst,
    const u16* __restrict__ w1T, const float* __restrict__ b1,
    const u16* __restrict__ w2T, const float* __restrict__ b2,
    float* agg)
{
    __shared__ u16 aC[64 * 32];           // [64 rows][32 k] bf16
    __shared__ u16 bC[256 * 32];          // [256 n][32 k] bf16
    __shared__ u16 hL[64 * 272];          // [64 e][256 h + 16 pad], 544B rows
    __shared__ int ssrc[64];
    __shared__ int sdst[64];

    const int tid = threadIdx.x;
    const int e0 = blockIdx.x * 64;
    if (tid < 64) {
        int e = e0 + tid;
        ssrc[tid] = (e < NE) ? esrc[e] : 0;
        sdst[tid] = (e < NE) ? edst[e] : 0;
    }

    const int wv = tid >> 6;
    const int lane = tid & 63;
    const int m = lane & 15;
    const int q = lane >> 4;
    const int sr = tid >> 2;              // staging row 0..63
    const int sc8 = (tid & 3) * 8;        // staging col (8 f32 per lane)

    f32x4 zero = {0.f, 0.f, 0.f, 0.f};
    f32x4 acc[4][4];
    #pragma unroll
    for (int i = 0; i < 4; ++i)
        #pragma unroll
        for (int j = 0; j < 4; ++j) acc[i][j] = zero;

    __syncthreads();                      // indices visible

    // ---- GEMM1: K = 512 (concat mesh_x[src] | grid_x[dst]), f32 -> bf16 stage
    for (int kt = 0; kt < 16; ++kt) {
        const int kg = kt * 32;
        if (kt) __syncthreads();
        {
            const int col = kg + sc8;
            const float* p = (col < DD)
                ? (mesh_x + (size_t)ssrc[sr] * DD + col)
                : (grid_x + (size_t)sdst[sr] * DD + (col - DD));
            float4 v0 = *(const float4*)p;
            float4 v1 = *(const float4*)(p + 4);
            *(uint4*)&aC[sr * 32 + sc8] = pack8(v0, v1);
        }
        #pragma unroll
        for (int i = 0; i < 4; ++i) {
            int flat = tid + 256 * i;
            int n = flat >> 2;
            int c = (flat & 3) * 8;
            *(uint4*)&bC[n * 32 + c] = *(const uint4*)(w1T + (size_t)n * 512 + kg + c);
        }
        __syncthreads();
        bf16x8 af[4], bfr[4];
        #pragma unroll
        for (int et = 0; et < 4; ++et)
            af[et] = *(const bf16x8*)&aC[(et * 16 + m) * 32 + q * 8];
        #pragma unroll
        for (int ht = 0; ht < 4; ++ht)
            bfr[ht] = *(const bf16x8*)&bC[(wv * 64 + ht * 16 + m) * 32 + q * 8];
        #pragma unroll
        for (int ht = 0; ht < 4; ++ht)
            #pragma unroll
            for (int et = 0; et < 4; ++et)
                acc[ht][et] = __builtin_amdgcn_mfma_f32_16x16x32_bf16(
                    bfr[ht], af[et], acc[ht][et], 0, 0, 0);
    }

    // ---- epilogue 1: bias + relu -> hL[edge][hidden] bf16
    #pragma unroll
    for (int ht = 0; ht < 4; ++ht) {
        const int hb = wv * 64 + ht * 16 + q * 4;
        const float4 bb = *(const float4*)(b1 + hb);
        #pragma unroll
        for (int et = 0; et < 4; ++et) {
            const int e = et * 16 + m;
            ushort4 o;
            o.x = f2bf(fmaxf(acc[ht][et][0] + bb.x, 0.f));
            o.y = f2bf(fmaxf(acc[ht][et][1] + bb.y, 0.f));
            o.z = f2bf(fmaxf(acc[ht][et][2] + bb.z, 0.f));
            o.w = f2bf(fmaxf(acc[ht][et][3] + bb.w, 0.f));
            *(ushort4*)&hL[e * 272 + hb] = o;
        }
    }
    #pragma unroll
    for (int i = 0; i < 4; ++i)
        #pragma unroll
        for (int j = 0; j < 4; ++j) acc[i][j] = zero;
    __syncthreads();                      // hL visible to all waves

    // ---- GEMM2: K = 256
    for (int kt = 0; kt < 8; ++kt) {
        const int kg = kt * 32;
        if (kt) __syncthreads();
        #pragma unroll
        for (int i = 0; i < 4; ++i) {
            int flat = tid + 256 * i;
            int n = flat >> 2;
            int c = (flat & 3) * 8;
            *(uint4*)&bC[n * 32 + c] = *(const uint4*)(w2T + (size_t)n * 256 + kg + c);
        }
        __syncthreads();
        bf16x8 af[4], bfr[4];
        #pragma unroll
        for (int et = 0; et < 4; ++et)
            af[et] = *(const bf16x8*)&hL[(et * 16 + m) * 272 + kg + q * 8];
        #pragma unroll
        for (int ht = 0; ht < 4; ++ht)
            bfr[ht] = *(const bf16x8*)&bC[(wv * 64 + ht * 16 + m) * 32 + q * 8];
        #pragma unroll
        for (int ht = 0; ht < 4; ++ht)
            #pragma unroll
            for (int et = 0; et < 4; ++et)
                acc[ht][et] = __builtin_amdgcn_mfma_f32_16x16x32_bf16(
                    bfr[ht], af[et], acc[ht][et], 0, 0, 0);
    }

    // ---- epilogue 2: scatter-add edge_new into agg (f32 HW atomics)
    #pragma unroll
    for (int nt = 0; nt < 4; ++nt) {
        const int nb = wv * 64 + nt * 16 + q * 4;
        const float4 bb = *(const float4*)(b2 + nb);
        #pragma unroll
        for (int et = 0; et < 4; ++et) {
            const int el = et * 16 + m;
            if (e0 + el < NE) {
                float* p = agg + (size_t)sdst[el] * HH + nb;
                unsafeAtomicAdd(p + 0, acc[nt][et][0] + bb.x);
                unsafeAtomicAdd(p + 1, acc[nt][et][1] + bb.y);
                unsafeAtomicAdd(p + 2, acc[nt][et][2] + bb.z);
                unsafeAtomicAdd(p + 3, acc[nt][et][3] + bb.w);
            }
        }
    }
}

// ---------------- grid MLP + residual ----------------
// agg is f32 [NG][HH] living in d_out; each block reads only the rows it
// later overwrites with the final f32 output (block-local read-then-write).
// NOTE: agg and out alias — no __restrict__ on them.
__global__ __launch_bounds__(256, 2) void grid_mlp(
    const float* __restrict__ grid_x, const float* agg,
    const u16* __restrict__ w1T, const float* __restrict__ b1,
    const u16* __restrict__ w2T, const float* __restrict__ b2,
    float* out)
{
    __shared__ u16 aC[64 * 32];
    __shared__ u16 bC[256 * 32];
    __shared__ u16 hL[64 * 272];

    const int tid = threadIdx.x;
    const int r0 = blockIdx.x * 64;
    const int wv = tid >> 6;
    const int lane = tid & 63;
    const int m = lane & 15;
    const int q = lane >> 4;
    const int sr = tid >> 2;
    const int sc8 = (tid & 3) * 8;
    int srow = r0 + sr; if (srow >= NG) srow = NG - 1;  // clamp stays inside this block's rows

    f32x4 zero = {0.f, 0.f, 0.f, 0.f};
    f32x4 acc[4][4];
    #pragma unroll
    for (int i = 0; i < 4; ++i)
        #pragma unroll
        for (int j = 0; j < 4; ++j) acc[i][j] = zero;

    // ---- GEMM1: K = 512 (concat grid_x | agg), f32 -> bf16 stage
    for (int kt = 0; kt < 16; ++kt) {
        const int kg = kt * 32;
        if (kt) __syncthreads();
        {
            const int col = kg + sc8;
            const float* p = (col < DD)
                ? (grid_x + (size_t)srow * DD + col)
                : (agg + (size_t)srow * HH + (col - DD));
            float4 v0 = *(const float4*)p;
            float4 v1 = *(const float4*)(p + 4);
            *(uint4*)&aC[sr * 32 + sc8] = pack8(v0, v1);
        }
        #pragma unroll
        for (int i = 0; i < 4; ++i) {
            int flat = tid + 256 * i;
            int n = flat >> 2;
            int c = (flat & 3) * 8;
            *(uint4*)&bC[n * 32 + c] = *(const uint4*)(w1T + (size_t)n * 512 + kg + c);
        }
        __syncthreads();
        bf16x8 af[4], bfr[4];
        #pragma unroll
        for (int et = 0; et < 4; ++et)
            af[et] = *(const bf16x8*)&aC[(et * 16 + m) * 32 + q * 8];
        #pragma unroll
        for (int ht = 0; ht < 4; ++ht)
            bfr[ht] = *(const bf16x8*)&bC[(wv * 64 + ht * 16 + m) * 32 + q * 8];
        #pragma unroll
        for (int ht = 0; ht < 4; ++ht)
            #pragma unroll
            for (int et = 0; et < 4; ++et)
                acc[ht][et] = __builtin_amdgcn_mfma_f32_16x16x32_bf16(
                    bfr[ht], af[et], acc[ht][et], 0, 0, 0);
    }

    #pragma unroll
    for (int ht = 0; ht < 4; ++ht) {
        const int hb = wv * 64 + ht * 16 + q * 4;
        const float4 bb = *(const float4*)(b1 + hb);
        #pragma unroll
        for (int et = 0; et < 4; ++et) {
            const int e = et * 16 + m;
            ushort4 o;
            o.x = f2bf(fmaxf(acc[ht][et][0] + bb.x, 0.f));
            o.y = f2bf(fmaxf(acc[ht][et][1] + bb.y, 0.f));
            o.z = f2bf(fmaxf(acc[ht][et][2] + bb.z, 0.f));
            o.w = f2bf(fmaxf(acc[ht][et][3] + bb.w, 0.f));
            *(ushort4*)&hL[e * 272 + hb] = o;
        }
    }
    #pragma unroll
    for (int i = 0; i < 4; ++i)
        #pragma unroll
        for (int j = 0; j < 4; ++j) acc[i][j] = zero;
    __syncthreads();

    // ---- GEMM2: K = 256
    for (int kt = 0; kt < 8; ++kt) {
        const int kg = kt * 32;
        if (kt) __syncthreads();
        #pragma unroll
        for (int i = 0; i < 4; ++i) {
            int flat = tid + 256 * i;
            int n = flat >> 2;
            int c = (flat & 3) * 8;
            *(uint4*)&bC[n * 32 + c] = *(const uint4*)(w2T + (size_t)n * 256 + kg + c);
        }
        __syncthreads();
        bf16x8 af[4], bfr[4];
        #pragma unroll
        for (int et = 0; et < 4; ++et)
            af[et] = *(const bf16x8*)&hL[(et * 16 + m) * 272 + kg + q * 8];
        #pragma unroll
        for (int ht = 0; ht < 4; ++ht)
            bfr[ht] = *(const bf16x8*)&bC[(wv * 64 + ht * 16 + m) * 32 + q * 8];
        #pragma unroll
        for (int ht = 0; ht < 4; ++ht)
            #pragma unroll
            for (int et = 0; et < 4; ++et)
                acc[ht][et] = __builtin_amdgcn_mfma_f32_16x16x32_bf16(
                    bfr[ht], af[et], acc[ht][et], 0, 0, 0);
    }

    // ---- epilogue: + b2 + residual grid_x, store f32 (overwrites agg rows)
    #pragma unroll
    for (int nt = 0; nt < 4; ++nt) {
        const int nb = wv * 64 + nt * 16 + q * 4;
        const float4 bb = *(const float4*)(b2 + nb);
        #pragma unroll
        for (int et = 0; et < 4; ++et) {
            const int r = r0 + et * 16 + m;
            if (r < NG) {
                const float4 g = *(const float4*)(grid_x + (size_t)r * DD + nb);
                float4 o;
                o.x = acc[nt][et][0] + bb.x + g.x;
                o.y = acc[nt][et][1] + bb.y + g.y;
                o.z = acc[nt][et][2] + bb.z + g.z;
                o.w = acc[nt][et][3] + bb.w + g.w;
                *(float4*)(out + (size_t)r * DD + nb) = o;
            }
        }
    }
}

extern "C" void kernel_launch(void* const* d_in, const int* in_sizes, int n_in,
                              void* d_out, int out_size, void* d_ws, size_t ws_size,
                              hipStream_t stream)
{
    const float* mesh_x = (const float*)d_in[0];
    const float* grid_x = (const float*)d_in[1];
    const int* esrc     = (const int*)d_in[2];
    const int* edst     = (const int*)d_in[3];
    const float* w1e    = (const float*)d_in[4];
    const float* b1e    = (const float*)d_in[5];
    const float* w2e    = (const float*)d_in[6];
    const float* b2e    = (const float*)d_in[7];
    const float* w1g    = (const float*)d_in[8];
    const float* b1g    = (const float*)d_in[9];
    const float* w2g    = (const float*)d_in[10];
    const float* b2g    = (const float*)d_in[11];
    float* out = (float*)d_out;

    // d_ws: 4 transposed bf16 weight matrices (786 KB total)
    u16* w1eT = (u16*)d_ws;
    u16* w2eT = w1eT + 512 * 256;
    u16* w1gT = w2eT + 256 * 256;
    u16* w2gT = w1gT + 512 * 256;

    // agg f32 [NG][HH] lives in d_out (exactly out_size elements); zero it.
    hipMemsetAsync(d_out, 0, (size_t)NG * HH * sizeof(float), stream);

    transpose_f32_to_bf16T<<<32, 256, 0, stream>>>(w1e, w1eT, 512, 256);
    transpose_f32_to_bf16T<<<16, 256, 0, stream>>>(w2e, w2eT, 256, 256);
    transpose_f32_to_bf16T<<<32, 256, 0, stream>>>(w1g, w1gT, 512, 256);
    transpose_f32_to_bf16T<<<16, 256, 0, stream>>>(w2g, w2gT, 256, 256);

    edge_mlp<<<(NE + 63) / 64, 256, 0, stream>>>(
        mesh_x, grid_x, esrc, edst, w1eT, b1e, w2eT, b2e, (float*)d_out);
    grid_mlp<<<(NG + 63) / 64, 256, 0, stream>>>(
        grid_x, (const float*)d_out, w1gT, b1g, w2gT, b2g, out);
}